// Round 3
// baseline (2092.071 us; speedup 1.0000x reference)
//
#include <hip/hip_runtime.h>

#define N_LINKS 262144
#define N_PAIRS 4194304
#define F 20
#define T_ITERS 4
#define NBUCK 4096              // buckets of 64 links: bucket = second >> 6
#define LPB 64                  // links per bucket

__device__ __forceinline__ float selu_f(float x) {
    const float scale = 1.0507009873554805f;
    const float scale_alpha = 1.7580993408473766f;  // scale * alpha
    return x > 0.0f ? scale * x : scale_alpha * (__expf(x) - 1.0f);
}

__device__ __forceinline__ float sigmoid_f(float x) {
    return 1.0f / (1.0f + __expf(-x));
}

__device__ __forceinline__ float tanh_fast(float x) {
    x = fminf(fmaxf(x, -15.0f), 15.0f);
    float e = __expf(2.0f * x);
    return (e - 1.0f) / (e + 1.0f);
}

// ---------------- CSR-by-bucket build (once per call) ----------------

// LDS histogram over 4096 buckets; few global atomics.
__global__ void k_hist(const int* __restrict__ second, int* __restrict__ bhist) {
    __shared__ int h[NBUCK];
    for (int i = threadIdx.x; i < NBUCK; i += blockDim.x) h[i] = 0;
    __syncthreads();
    for (int p = blockIdx.x * blockDim.x + threadIdx.x; p < N_PAIRS;
         p += gridDim.x * blockDim.x)
        atomicAdd(&h[second[p] >> 6], 1);
    __syncthreads();
    for (int i = threadIdx.x; i < NBUCK; i += blockDim.x) {
        int c = h[i];
        if (c) atomicAdd(&bhist[i], c);
    }
}

// Single-block exclusive scan over 4096 bucket counts.
__global__ void k_scan(const int* __restrict__ bhist,
                       int* __restrict__ bstart, int* __restrict__ bcursor) {
    __shared__ int sums[1024];
    const int tid = threadIdx.x;
    const int b0 = tid * 4;
    int local[4];
    int s = 0;
#pragma unroll
    for (int i = 0; i < 4; ++i) { local[i] = bhist[b0 + i]; s += local[i]; }
    sums[tid] = s;
    __syncthreads();
    for (int off = 1; off < 1024; off <<= 1) {
        int v = (tid >= off) ? sums[tid - off] : 0;
        __syncthreads();
        sums[tid] += v;
        __syncthreads();
    }
    int run = (tid == 0) ? 0 : sums[tid - 1];
#pragma unroll
    for (int i = 0; i < 4; ++i) {
        bstart[b0 + i] = run;
        bcursor[b0 + i] = run;
        run += local[i];
    }
    if (tid == 1023) bstart[NBUCK] = run;  // == N_PAIRS
}

// Per-block reservation partition: block LDS-hists its chunk, reserves one
// contiguous run per bucket (1 global atomic per nonzero bin per block),
// then writes packed entries {first:18 | second&63:6} into its runs.
#define FILL_BLOCKS 128
#define FILL_THREADS 1024
__global__ void __launch_bounds__(FILL_THREADS)
k_fill(const int* __restrict__ first, const int* __restrict__ second,
       int* __restrict__ bcursor, unsigned* __restrict__ sorted) {
    __shared__ int h[NBUCK];
    __shared__ int resv[NBUCK];
    const int chunk = N_PAIRS / FILL_BLOCKS;   // 32768
    const int base = blockIdx.x * chunk;
    for (int i = threadIdx.x; i < NBUCK; i += blockDim.x) h[i] = 0;
    __syncthreads();
    for (int i = threadIdx.x; i < chunk; i += blockDim.x)
        atomicAdd(&h[second[base + i] >> 6], 1);
    __syncthreads();
    for (int i = threadIdx.x; i < NBUCK; i += blockDim.x) {
        int c = h[i];
        resv[i] = c ? atomicAdd(&bcursor[i], c) : 0;
        h[i] = 0;  // reuse as local cursor
    }
    __syncthreads();
    for (int i = threadIdx.x; i < chunk; i += blockDim.x) {
        int s = second[base + i];
        int b = s >> 6;
        int pos = resv[b] + atomicAdd(&h[b], 1);
        sorted[pos] = (unsigned)first[base + i] | ((unsigned)(s & 63) << 18);
    }
}

// ---------------- per-iteration kernels ----------------

// X1[l] = W1 @ state[l] + b_msg ; X2[l] = W2 @ state[l]  (used once, t=0)
__global__ void k_premsg(const float* __restrict__ state,
                         const float* __restrict__ W_msg,
                         const float* __restrict__ b_msg,
                         float* __restrict__ X1, float* __restrict__ X2) {
    __shared__ float Wl[F * 2 * F];
    __shared__ float bl[F];
    for (int i = threadIdx.x; i < F * 2 * F; i += blockDim.x) Wl[i] = W_msg[i];
    if (threadIdx.x < F) bl[threadIdx.x] = b_msg[threadIdx.x];
    __syncthreads();

    int l = blockIdx.x * blockDim.x + threadIdx.x;

    float s[F];
    const float4* sp = (const float4*)(state + (size_t)l * F);
#pragma unroll
    for (int i = 0; i < 5; ++i) {
        float4 v = sp[i];
        s[4*i+0] = v.x; s[4*i+1] = v.y; s[4*i+2] = v.z; s[4*i+3] = v.w;
    }
    float o1[F], o2[F];
#pragma unroll
    for (int o = 0; o < F; ++o) {
        float a1 = bl[o], a2 = 0.0f;
#pragma unroll
        for (int k = 0; k < F; ++k) {
            a1 = fmaf(Wl[o * 2 * F + k],     s[k], a1);
            a2 = fmaf(Wl[o * 2 * F + F + k], s[k], a2);
        }
        o1[o] = a1; o2[o] = a2;
    }
    float4* x1p = (float4*)(X1 + (size_t)l * F);
    float4* x2p = (float4*)(X2 + (size_t)l * F);
#pragma unroll
    for (int i = 0; i < 5; ++i) {
        x1p[i] = make_float4(o1[4*i], o1[4*i+1], o1[4*i+2], o1[4*i+3]);
        x2p[i] = make_float4(o2[4*i], o2[4*i+1], o2[4*i+2], o2[4*i+3]);
    }
}

// One block per bucket: LDS-stage X2 slice + LDS accumulator; 12 subgroups of
// 20 lanes stream the bucket's pairs; coalesced 80B X1 row gathers; LDS float
// atomics (consecutive banks, <=2-way); coalesced 5KB store.
__global__ void __launch_bounds__(256) k_agg(const int* __restrict__ bstart,
                                             const unsigned* __restrict__ sorted,
                                             const float* __restrict__ X1,
                                             const float* __restrict__ X2,
                                             float* __restrict__ agg) {
    __shared__ float aggL[LPB * F];  // 5120 B
    __shared__ float x2L[LPB * F];   // 5120 B
    const int b = blockIdx.x;
    const int linkBase = b * LPB;
    for (int i = threadIdx.x; i < LPB * F; i += 256) {
        aggL[i] = 0.0f;
        x2L[i] = X2[(size_t)linkBase * F + i];
    }
    __syncthreads();
    const int start = bstart[b], end = bstart[b + 1];
    const int sg = threadIdx.x / F;          // 0..12
    const int f  = threadIdx.x - sg * F;
    if (sg < 12) {
        for (int p = start + sg; p < end; p += 12) {
            unsigned e = sorted[p];
            int src = e & 0x3FFFF;
            int sl  = e >> 18;
            float v = selu_f(X1[(size_t)src * F + f] + x2L[sl * F + f]);
            atomicAdd(&aggL[sl * F + f], v);
        }
    }
    __syncthreads();
    for (int i = threadIdx.x; i < LPB * F; i += 256)
        agg[(size_t)linkBase * F + i] = aggL[i];
}

// GRU cell fused with next-iteration premsg (flags&1) and final feature
// reduction (flags&2). Grid covers N_LINKS exactly; no early returns.
__global__ void __launch_bounds__(256)
k_gru(const float* __restrict__ agg, const float* __restrict__ h_in,
      const float* __restrict__ W_ih, const float* __restrict__ W_hh,
      const float* __restrict__ b_ih, const float* __restrict__ b_hh,
      const float* __restrict__ W_msg, const float* __restrict__ b_msg,
      float* __restrict__ h_out, float* __restrict__ X1, float* __restrict__ X2,
      float* __restrict__ feature, int flags) {
    __shared__ float Wi[3 * F * F];
    __shared__ float Wh[3 * F * F];
    __shared__ float Wm[F * 2 * F];
    __shared__ float bi[3 * F];
    __shared__ float bh[3 * F];
    __shared__ float bm[F];
    __shared__ float red[4 * F];
    for (int i = threadIdx.x; i < 3 * F * F; i += blockDim.x) {
        Wi[i] = W_ih[i];
        Wh[i] = W_hh[i];
    }
    for (int i = threadIdx.x; i < F * 2 * F; i += blockDim.x) Wm[i] = W_msg[i];
    if (threadIdx.x < 3 * F) {
        bi[threadIdx.x] = b_ih[threadIdx.x];
        bh[threadIdx.x] = b_hh[threadIdx.x];
    }
    if (threadIdx.x < F) bm[threadIdx.x] = b_msg[threadIdx.x];
    __syncthreads();

    const int l = blockIdx.x * blockDim.x + threadIdx.x;

    float m[F], h[F];
    const float4* mp = (const float4*)(agg  + (size_t)l * F);
    const float4* hp = (const float4*)(h_in + (size_t)l * F);
#pragma unroll
    for (int i = 0; i < 5; ++i) {
        float4 vm = mp[i], vh = hp[i];
        m[4*i+0] = vm.x; m[4*i+1] = vm.y; m[4*i+2] = vm.z; m[4*i+3] = vm.w;
        h[4*i+0] = vh.x; h[4*i+1] = vh.y; h[4*i+2] = vh.z; h[4*i+3] = vh.w;
    }

    float hn[F];
#pragma unroll
    for (int j = 0; j < F; ++j) {
        float gr = bi[j]     + bh[j];
        float gz = bi[F + j] + bh[F + j];
        float gi_n = bi[2*F + j];
        float gh_n = bh[2*F + j];
        float gr_i = 0.f, gz_i = 0.f, gr_h = 0.f, gz_h = 0.f;
#pragma unroll
        for (int k = 0; k < F; ++k) {
            gr_i = fmaf(Wi[(0*F + j) * F + k], m[k], gr_i);
            gz_i = fmaf(Wi[(1*F + j) * F + k], m[k], gz_i);
            gi_n = fmaf(Wi[(2*F + j) * F + k], m[k], gi_n);
            gr_h = fmaf(Wh[(0*F + j) * F + k], h[k], gr_h);
            gz_h = fmaf(Wh[(1*F + j) * F + k], h[k], gz_h);
            gh_n = fmaf(Wh[(2*F + j) * F + k], h[k], gh_n);
        }
        float r = sigmoid_f(gr + gr_i + gr_h);
        float z = sigmoid_f(gz + gz_i + gz_h);
        float n = tanh_fast(gi_n + r * gh_n);
        hn[j] = (1.0f - z) * n + z * h[j];
    }

    float4* op = (float4*)(h_out + (size_t)l * F);
#pragma unroll
    for (int i = 0; i < 5; ++i)
        op[i] = make_float4(hn[4*i], hn[4*i+1], hn[4*i+2], hn[4*i+3]);

    if (flags & 1) {  // premsg for next iteration from hn
        float o1[F], o2[F];
#pragma unroll
        for (int o = 0; o < F; ++o) {
            float a1 = bm[o], a2 = 0.0f;
#pragma unroll
            for (int k = 0; k < F; ++k) {
                a1 = fmaf(Wm[o * 2 * F + k],     hn[k], a1);
                a2 = fmaf(Wm[o * 2 * F + F + k], hn[k], a2);
            }
            o1[o] = a1; o2[o] = a2;
        }
        float4* x1p = (float4*)(X1 + (size_t)l * F);
        float4* x2p = (float4*)(X2 + (size_t)l * F);
#pragma unroll
        for (int i = 0; i < 5; ++i) {
            x1p[i] = make_float4(o1[4*i], o1[4*i+1], o1[4*i+2], o1[4*i+3]);
            x2p[i] = make_float4(o2[4*i], o2[4*i+1], o2[4*i+2], o2[4*i+3]);
        }
    }

    if (flags & 2) {  // feature reduction: sum hn over all links
#pragma unroll
        for (int off = 1; off < 64; off <<= 1) {
#pragma unroll
            for (int j = 0; j < F; ++j) hn[j] += __shfl_xor(hn[j], off, 64);
        }
        const int lane = threadIdx.x & 63;
        const int wave = threadIdx.x >> 6;
        if (lane == 0) {
#pragma unroll
            for (int j = 0; j < F; ++j) red[wave * F + j] = hn[j];
        }
        __syncthreads();
        if (threadIdx.x < F) {
            float s = red[threadIdx.x] + red[F + threadIdx.x] +
                      red[2 * F + threadIdx.x] + red[3 * F + threadIdx.x];
            atomicAdd(&feature[threadIdx.x], s);
        }
    }
}

__global__ void k_readout(const float* __restrict__ feature,
                          const float* __restrict__ W_r1, const float* __restrict__ b_r1,
                          const float* __restrict__ W_r2, const float* __restrict__ b_r2,
                          const float* __restrict__ W_out, const float* __restrict__ b_out,
                          float* __restrict__ out) {
    if (threadIdx.x != 0 || blockIdx.x != 0) return;
    float fv[F], h1[F], h2[F];
#pragma unroll
    for (int i = 0; i < F; ++i) fv[i] = feature[i];
#pragma unroll
    for (int o = 0; o < F; ++o) {
        float a = b_r1[o];
#pragma unroll
        for (int k = 0; k < F; ++k) a = fmaf(W_r1[o * F + k], fv[k], a);
        h1[o] = selu_f(a);
    }
#pragma unroll
    for (int o = 0; o < F; ++o) {
        float a = b_r2[o];
#pragma unroll
        for (int k = 0; k < F; ++k) a = fmaf(W_r2[o * F + k], h1[k], a);
        h2[o] = selu_f(a);
    }
    float a = b_out[0];
#pragma unroll
    for (int k = 0; k < F; ++k) a = fmaf(W_out[k], h2[k], a);
    out[0] = a;
}

extern "C" void kernel_launch(void* const* d_in, const int* in_sizes, int n_in,
                              void* d_out, int out_size, void* d_ws, size_t ws_size,
                              hipStream_t stream) {
    const float* link_state = (const float*)d_in[0];
    const int*   first      = (const int*)  d_in[1];
    const int*   second     = (const int*)  d_in[2];
    // d_in[3] = state_dim (unused)
    const float* W_msg = (const float*)d_in[4];
    const float* b_msg = (const float*)d_in[5];
    const float* W_ih  = (const float*)d_in[6];
    const float* W_hh  = (const float*)d_in[7];
    const float* b_ih  = (const float*)d_in[8];
    const float* b_hh  = (const float*)d_in[9];
    const float* W_r1  = (const float*)d_in[10];
    const float* b_r1  = (const float*)d_in[11];
    const float* W_r2  = (const float*)d_in[12];
    const float* b_r2  = (const float*)d_in[13];
    const float* W_out = (const float*)d_in[14];
    const float* b_out = (const float*)d_in[15];
    float* out = (float*)d_out;

    const size_t NF = (size_t)N_LINKS * F;
    float* state   = (float*)d_ws;        // 21 MB
    float* X1      = state + NF;          // 21 MB
    float* X2      = X1 + NF;             // 21 MB
    float* agg     = X2 + NF;             // 21 MB
    float* feature = agg + NF;            // 128 B slot
    int* bhist     = (int*)(feature + 32);
    int* bstart    = bhist + NBUCK;       // NBUCK+1
    int* bcursor   = bstart + NBUCK + 1;
    unsigned* sorted = (unsigned*)(bcursor + NBUCK);  // 16.8 MB

    hipMemsetAsync(bhist, 0, NBUCK * sizeof(int), stream);
    hipMemsetAsync(feature, 0, F * sizeof(float), stream);

    k_hist<<<128, 512, 0, stream>>>(second, bhist);
    k_scan<<<1, 1024, 0, stream>>>(bhist, bstart, bcursor);
    k_fill<<<FILL_BLOCKS, FILL_THREADS, 0, stream>>>(first, second, bcursor, sorted);

    k_premsg<<<N_LINKS / 256, 256, 0, stream>>>(link_state, W_msg, b_msg, X1, X2);
    for (int t = 0; t < T_ITERS; ++t) {
        const float* h = (t == 0) ? link_state : state;
        int flags = (t < T_ITERS - 1 ? 1 : 0) | (t == T_ITERS - 1 ? 2 : 0);
        k_agg<<<NBUCK, 256, 0, stream>>>(bstart, sorted, X1, X2, agg);
        k_gru<<<N_LINKS / 256, 256, 0, stream>>>(agg, h, W_ih, W_hh, b_ih, b_hh,
                                                 W_msg, b_msg, state, X1, X2,
                                                 feature, flags);
    }
    k_readout<<<1, 64, 0, stream>>>(feature, W_r1, b_r1, W_r2, b_r2, W_out, b_out, out);
}

// Round 4
// 1041.115 us; speedup vs baseline: 2.0095x; 2.0095x over previous
//
#include <hip/hip_runtime.h>
#include <hip/hip_fp16.h>

#define N_LINKS 262144
#define N_PAIRS 4194304
#define F 20
#define XS 32                   // padded X1h row stride in halfs (64 B)
#define T_ITERS 4
#define NBUCK 4096              // buckets of 64 links: bucket = second >> 6
#define LPB 64                  // links per bucket
#define BCAP 2048               // max pairs staged per bucket (mean 1024)

__device__ __forceinline__ float selu_f(float x) {
    const float scale = 1.0507009873554805f;
    const float scale_alpha = 1.7580993408473766f;  // scale * alpha
    return x > 0.0f ? scale * x : scale_alpha * (__expf(x) - 1.0f);
}

__device__ __forceinline__ float sigmoid_f(float x) {
    return 1.0f / (1.0f + __expf(-x));
}

__device__ __forceinline__ float tanh_fast(float x) {
    x = fminf(fmaxf(x, -15.0f), 15.0f);
    float e = __expf(2.0f * x);
    return (e - 1.0f) / (e + 1.0f);
}

// ---------------- CSR build (once per call; graph is static) ----------------

__global__ void k_hist(const int* __restrict__ second, int* __restrict__ bhist) {
    __shared__ int h[NBUCK];
    for (int i = threadIdx.x; i < NBUCK; i += blockDim.x) h[i] = 0;
    __syncthreads();
    for (int p = blockIdx.x * blockDim.x + threadIdx.x; p < N_PAIRS;
         p += gridDim.x * blockDim.x)
        atomicAdd(&h[second[p] >> 6], 1);
    __syncthreads();
    for (int i = threadIdx.x; i < NBUCK; i += blockDim.x) {
        int c = h[i];
        if (c) atomicAdd(&bhist[i], c);
    }
}

__global__ void k_scan(const int* __restrict__ bhist,
                       int* __restrict__ bstart, int* __restrict__ bcursor,
                       int* __restrict__ rs) {
    __shared__ int sums[1024];
    const int tid = threadIdx.x;
    const int b0 = tid * 4;
    int local[4];
    int s = 0;
#pragma unroll
    for (int i = 0; i < 4; ++i) { local[i] = bhist[b0 + i]; s += local[i]; }
    sums[tid] = s;
    __syncthreads();
    for (int off = 1; off < 1024; off <<= 1) {
        int v = (tid >= off) ? sums[tid - off] : 0;
        __syncthreads();
        sums[tid] += v;
        __syncthreads();
    }
    int run = (tid == 0) ? 0 : sums[tid - 1];
#pragma unroll
    for (int i = 0; i < 4; ++i) {
        bstart[b0 + i] = run;
        bcursor[b0 + i] = run;
        run += local[i];
    }
    if (tid == 1023) { bstart[NBUCK] = run; rs[N_LINKS] = run; }
}

// Per-block reservation partition into buckets; entry = {first:18 | dst&63:6}.
#define FILL_BLOCKS 128
#define FILL_THREADS 1024
__global__ void __launch_bounds__(FILL_THREADS)
k_fill(const int* __restrict__ first, const int* __restrict__ second,
       int* __restrict__ bcursor, unsigned* __restrict__ sortedA) {
    __shared__ int h[NBUCK];
    __shared__ int resv[NBUCK];
    const int chunk = N_PAIRS / FILL_BLOCKS;   // 32768
    const int base = blockIdx.x * chunk;
    for (int i = threadIdx.x; i < NBUCK; i += blockDim.x) h[i] = 0;
    __syncthreads();
    for (int i = threadIdx.x; i < chunk; i += blockDim.x)
        atomicAdd(&h[second[base + i] >> 6], 1);
    __syncthreads();
    for (int i = threadIdx.x; i < NBUCK; i += blockDim.x) {
        int c = h[i];
        resv[i] = c ? atomicAdd(&bcursor[i], c) : 0;
        h[i] = 0;  // reuse as local cursor
    }
    __syncthreads();
    for (int i = threadIdx.x; i < chunk; i += blockDim.x) {
        int s = second[base + i];
        int b = s >> 6;
        int pos = resv[b] + atomicAdd(&h[b], 1);
        sortedA[pos] = (unsigned)first[base + i] | ((unsigned)(s & 63) << 18);
    }
}

// One block per bucket: in-LDS counting sort -> per-link CSR (rs + srcs).
__global__ void __launch_bounds__(256)
k_refine(const int* __restrict__ bstart, const unsigned* __restrict__ sortedA,
         int* __restrict__ srcs, int* __restrict__ rs) {
    __shared__ unsigned ent[BCAP];
    __shared__ int outv[BCAP];
    __shared__ int cnt[LPB];
    __shared__ int off[LPB];
    const int b = blockIdx.x;
    const int s = bstart[b];
    int n = bstart[b + 1] - s;
    if (n > BCAP) n = BCAP;  // statistically impossible (mean 1024, 30+ sigma)
    for (int i = threadIdx.x; i < n; i += 256) ent[i] = sortedA[s + i];
    if (threadIdx.x < LPB) cnt[threadIdx.x] = 0;
    __syncthreads();
    for (int i = threadIdx.x; i < n; i += 256)
        atomicAdd(&cnt[ent[i] >> 18], 1);
    __syncthreads();
    if (threadIdx.x < LPB) {
        int acc = 0;
        for (int j = 0; j < threadIdx.x; ++j) acc += cnt[j];
        off[threadIdx.x] = acc;
        rs[b * LPB + threadIdx.x] = s + acc;
    }
    __syncthreads();
    for (int i = threadIdx.x; i < n; i += 256) {
        unsigned v = ent[i];
        int pos = atomicAdd(&off[v >> 18], 1);
        outv[pos] = (int)(v & 0x3FFFF);
    }
    __syncthreads();
    for (int i = threadIdx.x; i < n; i += 256) srcs[s + i] = outv[i];
}

// ---------------- per-iteration kernels ----------------

// X1h[l] = fp16(W1 @ state[l] + b_msg), padded 64B rows ; X2[l] = W2 @ state[l]
__global__ void k_premsg(const float* __restrict__ state,
                         const float* __restrict__ W_msg,
                         const float* __restrict__ b_msg,
                         __half* __restrict__ X1h, float* __restrict__ X2) {
    __shared__ float Wl[F * 2 * F];
    __shared__ float bl[F];
    for (int i = threadIdx.x; i < F * 2 * F; i += blockDim.x) Wl[i] = W_msg[i];
    if (threadIdx.x < F) bl[threadIdx.x] = b_msg[threadIdx.x];
    __syncthreads();

    int l = blockIdx.x * blockDim.x + threadIdx.x;

    float s[F];
    const float4* sp = (const float4*)(state + (size_t)l * F);
#pragma unroll
    for (int i = 0; i < 5; ++i) {
        float4 v = sp[i];
        s[4*i+0] = v.x; s[4*i+1] = v.y; s[4*i+2] = v.z; s[4*i+3] = v.w;
    }
    float o1[F], o2[F];
#pragma unroll
    for (int o = 0; o < F; ++o) {
        float a1 = bl[o], a2 = 0.0f;
#pragma unroll
        for (int k = 0; k < F; ++k) {
            a1 = fmaf(Wl[o * 2 * F + k],     s[k], a1);
            a2 = fmaf(Wl[o * 2 * F + F + k], s[k], a2);
        }
        o1[o] = a1; o2[o] = a2;
    }
    __half2* xp = (__half2*)(X1h + (size_t)l * XS);
#pragma unroll
    for (int i = 0; i < 10; ++i)
        xp[i] = __halves2half2(__float2half(o1[2*i]), __float2half(o1[2*i+1]));
    float4* x2p = (float4*)(X2 + (size_t)l * F);
#pragma unroll
    for (int i = 0; i < 5; ++i)
        x2p[i] = make_float4(o2[4*i], o2[4*i+1], o2[4*i+2], o2[4*i+3]);
}

// Wave-per-link gather-aggregate, register accumulation, fp16 64B-row gathers.
__global__ void __launch_bounds__(256)
k_agg(const int* __restrict__ rs, const int* __restrict__ srcs,
      const __half* __restrict__ X1h, const float* __restrict__ X2,
      float* __restrict__ agg) {
    const int wave = threadIdx.x >> 6;
    const int l = blockIdx.x * 4 + wave;
    const int lane = threadIdx.x & 63;
    const int g = lane / F;            // 0..3 (g==3 idle)
    const int f = lane % F;

    const float x2f = X2[(size_t)l * F + f];
    const int row_start = rs[l];
    const int row_end = rs[l + 1];

    float acc = 0.0f;
    if (g < 3) {
        for (int p = row_start + g; p < row_end; p += 3) {
            int src = srcs[p];
            float x1 = __half2float(X1h[(size_t)src * XS + f]);
            acc += selu_f(x1 + x2f);
        }
    }
    float a1 = __shfl(acc, (lane + 20) & 63, 64);
    float a2 = __shfl(acc, (lane + 40) & 63, 64);
    if (lane < F) agg[(size_t)l * F + lane] = acc + a1 + a2;
}

// GRU fused with next-iteration premsg (flags&1) and feature reduce (flags&2).
__global__ void __launch_bounds__(256)
k_gru(const float* __restrict__ agg, const float* __restrict__ h_in,
      const float* __restrict__ W_ih, const float* __restrict__ W_hh,
      const float* __restrict__ b_ih, const float* __restrict__ b_hh,
      const float* __restrict__ W_msg, const float* __restrict__ b_msg,
      float* __restrict__ h_out, __half* __restrict__ X1h, float* __restrict__ X2,
      float* __restrict__ feature, int flags) {
    __shared__ float Wi[3 * F * F];
    __shared__ float Wh[3 * F * F];
    __shared__ float Wm[F * 2 * F];
    __shared__ float bi[3 * F];
    __shared__ float bh[3 * F];
    __shared__ float bm[F];
    __shared__ float red[4 * F];
    for (int i = threadIdx.x; i < 3 * F * F; i += blockDim.x) {
        Wi[i] = W_ih[i];
        Wh[i] = W_hh[i];
    }
    for (int i = threadIdx.x; i < F * 2 * F; i += blockDim.x) Wm[i] = W_msg[i];
    if (threadIdx.x < 3 * F) {
        bi[threadIdx.x] = b_ih[threadIdx.x];
        bh[threadIdx.x] = b_hh[threadIdx.x];
    }
    if (threadIdx.x < F) bm[threadIdx.x] = b_msg[threadIdx.x];
    __syncthreads();

    const int l = blockIdx.x * blockDim.x + threadIdx.x;

    float m[F], h[F];
    const float4* mp = (const float4*)(agg  + (size_t)l * F);
    const float4* hp = (const float4*)(h_in + (size_t)l * F);
#pragma unroll
    for (int i = 0; i < 5; ++i) {
        float4 vm = mp[i], vh = hp[i];
        m[4*i+0] = vm.x; m[4*i+1] = vm.y; m[4*i+2] = vm.z; m[4*i+3] = vm.w;
        h[4*i+0] = vh.x; h[4*i+1] = vh.y; h[4*i+2] = vh.z; h[4*i+3] = vh.w;
    }

    float hn[F];
#pragma unroll
    for (int j = 0; j < F; ++j) {
        float gr = bi[j]     + bh[j];
        float gz = bi[F + j] + bh[F + j];
        float gi_n = bi[2*F + j];
        float gh_n = bh[2*F + j];
        float gr_i = 0.f, gz_i = 0.f, gr_h = 0.f, gz_h = 0.f;
#pragma unroll
        for (int k = 0; k < F; ++k) {
            gr_i = fmaf(Wi[(0*F + j) * F + k], m[k], gr_i);
            gz_i = fmaf(Wi[(1*F + j) * F + k], m[k], gz_i);
            gi_n = fmaf(Wi[(2*F + j) * F + k], m[k], gi_n);
            gr_h = fmaf(Wh[(0*F + j) * F + k], h[k], gr_h);
            gz_h = fmaf(Wh[(1*F + j) * F + k], h[k], gz_h);
            gh_n = fmaf(Wh[(2*F + j) * F + k], h[k], gh_n);
        }
        float r = sigmoid_f(gr + gr_i + gr_h);
        float z = sigmoid_f(gz + gz_i + gz_h);
        float n = tanh_fast(gi_n + r * gh_n);
        hn[j] = (1.0f - z) * n + z * h[j];
    }

    float4* op = (float4*)(h_out + (size_t)l * F);
#pragma unroll
    for (int i = 0; i < 5; ++i)
        op[i] = make_float4(hn[4*i], hn[4*i+1], hn[4*i+2], hn[4*i+3]);

    if (flags & 1) {  // premsg for next iteration from hn
        float o1[F], o2[F];
#pragma unroll
        for (int o = 0; o < F; ++o) {
            float a1 = bm[o], a2 = 0.0f;
#pragma unroll
            for (int k = 0; k < F; ++k) {
                a1 = fmaf(Wm[o * 2 * F + k],     hn[k], a1);
                a2 = fmaf(Wm[o * 2 * F + F + k], hn[k], a2);
            }
            o1[o] = a1; o2[o] = a2;
        }
        __half2* xp = (__half2*)(X1h + (size_t)l * XS);
#pragma unroll
        for (int i = 0; i < 10; ++i)
            xp[i] = __halves2half2(__float2half(o1[2*i]), __float2half(o1[2*i+1]));
        float4* x2p = (float4*)(X2 + (size_t)l * F);
#pragma unroll
        for (int i = 0; i < 5; ++i)
            x2p[i] = make_float4(o2[4*i], o2[4*i+1], o2[4*i+2], o2[4*i+3]);
    }

    if (flags & 2) {  // feature reduction: sum hn over all links
#pragma unroll
        for (int off = 1; off < 64; off <<= 1) {
#pragma unroll
            for (int j = 0; j < F; ++j) hn[j] += __shfl_xor(hn[j], off, 64);
        }
        const int lane = threadIdx.x & 63;
        const int wave = threadIdx.x >> 6;
        if (lane == 0) {
#pragma unroll
            for (int j = 0; j < F; ++j) red[wave * F + j] = hn[j];
        }
        __syncthreads();
        if (threadIdx.x < F) {
            float s = red[threadIdx.x] + red[F + threadIdx.x] +
                      red[2 * F + threadIdx.x] + red[3 * F + threadIdx.x];
            atomicAdd(&feature[threadIdx.x], s);
        }
    }
}

__global__ void k_readout(const float* __restrict__ feature,
                          const float* __restrict__ W_r1, const float* __restrict__ b_r1,
                          const float* __restrict__ W_r2, const float* __restrict__ b_r2,
                          const float* __restrict__ W_out, const float* __restrict__ b_out,
                          float* __restrict__ out) {
    if (threadIdx.x != 0 || blockIdx.x != 0) return;
    float fv[F], h1[F], h2[F];
#pragma unroll
    for (int i = 0; i < F; ++i) fv[i] = feature[i];
#pragma unroll
    for (int o = 0; o < F; ++o) {
        float a = b_r1[o];
#pragma unroll
        for (int k = 0; k < F; ++k) a = fmaf(W_r1[o * F + k], fv[k], a);
        h1[o] = selu_f(a);
    }
#pragma unroll
    for (int o = 0; o < F; ++o) {
        float a = b_r2[o];
#pragma unroll
        for (int k = 0; k < F; ++k) a = fmaf(W_r2[o * F + k], h1[k], a);
        h2[o] = selu_f(a);
    }
    float a = b_out[0];
#pragma unroll
    for (int k = 0; k < F; ++k) a = fmaf(W_out[k], h2[k], a);
    out[0] = a;
}

extern "C" void kernel_launch(void* const* d_in, const int* in_sizes, int n_in,
                              void* d_out, int out_size, void* d_ws, size_t ws_size,
                              hipStream_t stream) {
    const float* link_state = (const float*)d_in[0];
    const int*   first      = (const int*)  d_in[1];
    const int*   second     = (const int*)  d_in[2];
    // d_in[3] = state_dim (unused)
    const float* W_msg = (const float*)d_in[4];
    const float* b_msg = (const float*)d_in[5];
    const float* W_ih  = (const float*)d_in[6];
    const float* W_hh  = (const float*)d_in[7];
    const float* b_ih  = (const float*)d_in[8];
    const float* b_hh  = (const float*)d_in[9];
    const float* W_r1  = (const float*)d_in[10];
    const float* b_r1  = (const float*)d_in[11];
    const float* W_r2  = (const float*)d_in[12];
    const float* b_r2  = (const float*)d_in[13];
    const float* W_out = (const float*)d_in[14];
    const float* b_out = (const float*)d_in[15];
    float* out = (float*)d_out;

    const size_t NF = (size_t)N_LINKS * F;
    float* state   = (float*)d_ws;                    // 21 MB
    float* X2      = state + NF;                      // 21 MB
    float* agg     = X2 + NF;                         // 21 MB (aliases sortedA)
    __half* X1h    = (__half*)(agg + NF);             // 16.8 MB (64B rows)
    int*    srcs   = (int*)(X1h + (size_t)N_LINKS * XS);  // 16.8 MB
    int*    rs     = srcs + N_PAIRS;                  // 1 MB (+1)
    float* feature = (float*)(rs + N_LINKS + 1);      // 128 B slot
    int* bhist     = (int*)(feature + 32);
    int* bstart    = bhist + NBUCK;                   // NBUCK+1
    int* bcursor   = bstart + NBUCK + 1;
    unsigned* sortedA = (unsigned*)agg;               // lifetime: fill..refine only

    hipMemsetAsync(bhist, 0, NBUCK * sizeof(int), stream);
    hipMemsetAsync(feature, 0, F * sizeof(float), stream);

    k_hist<<<128, 512, 0, stream>>>(second, bhist);
    k_scan<<<1, 1024, 0, stream>>>(bhist, bstart, bcursor, rs);
    k_fill<<<FILL_BLOCKS, FILL_THREADS, 0, stream>>>(first, second, bcursor, sortedA);
    k_refine<<<NBUCK, 256, 0, stream>>>(bstart, sortedA, srcs, rs);

    k_premsg<<<N_LINKS / 256, 256, 0, stream>>>(link_state, W_msg, b_msg, X1h, X2);
    for (int t = 0; t < T_ITERS; ++t) {
        const float* h = (t == 0) ? link_state : state;
        int flags = (t < T_ITERS - 1 ? 1 : 0) | (t == T_ITERS - 1 ? 2 : 0);
        k_agg<<<N_LINKS / 4, 256, 0, stream>>>(rs, srcs, X1h, X2, agg);
        k_gru<<<N_LINKS / 256, 256, 0, stream>>>(agg, h, W_ih, W_hh, b_ih, b_hh,
                                                 W_msg, b_msg, state, X1h, X2,
                                                 feature, flags);
    }
    k_readout<<<1, 64, 0, stream>>>(feature, W_r1, b_r1, W_r2, b_r2, W_out, b_out, out);
}

// Round 5
// 1027.969 us; speedup vs baseline: 2.0352x; 1.0128x over previous
//
#include <hip/hip_runtime.h>
#include <hip/hip_fp16.h>

#define N_LINKS 262144
#define N_PAIRS 4194304
#define F 20
#define XS 32                   // padded X1h row stride in halfs (64 B)
#define T_ITERS 4
#define NBUCK 4096              // buckets of 64 links: bucket = second >> 6
#define LPB 64                  // links per bucket
#define BCAP 2048               // max pairs staged per bucket (mean 1024)

__device__ __forceinline__ float selu_f(float x) {
    const float scale = 1.0507009873554805f;
    const float scale_alpha = 1.7580993408473766f;  // scale * alpha
    return x > 0.0f ? scale * x : scale_alpha * (__expf(x) - 1.0f);
}

__device__ __forceinline__ float sigmoid_f(float x) {
    return 1.0f / (1.0f + __expf(-x));
}

__device__ __forceinline__ float tanh_fast(float x) {
    x = fminf(fmaxf(x, -15.0f), 15.0f);
    float e = __expf(2.0f * x);
    return (e - 1.0f) / (e + 1.0f);
}

// ---------------- CSR build (once per call; graph is static) ----------------

__global__ void k_hist(const int* __restrict__ second, int* __restrict__ bhist) {
    __shared__ int h[NBUCK];
    for (int i = threadIdx.x; i < NBUCK; i += blockDim.x) h[i] = 0;
    __syncthreads();
    for (int p = blockIdx.x * blockDim.x + threadIdx.x; p < N_PAIRS;
         p += gridDim.x * blockDim.x)
        atomicAdd(&h[second[p] >> 6], 1);
    __syncthreads();
    for (int i = threadIdx.x; i < NBUCK; i += blockDim.x) {
        int c = h[i];
        if (c) atomicAdd(&bhist[i], c);
    }
}

__global__ void k_scan(const int* __restrict__ bhist,
                       int* __restrict__ bstart, int* __restrict__ bcursor,
                       int* __restrict__ rs) {
    __shared__ int sums[1024];
    const int tid = threadIdx.x;
    const int b0 = tid * 4;
    int local[4];
    int s = 0;
#pragma unroll
    for (int i = 0; i < 4; ++i) { local[i] = bhist[b0 + i]; s += local[i]; }
    sums[tid] = s;
    __syncthreads();
    for (int off = 1; off < 1024; off <<= 1) {
        int v = (tid >= off) ? sums[tid - off] : 0;
        __syncthreads();
        sums[tid] += v;
        __syncthreads();
    }
    int run = (tid == 0) ? 0 : sums[tid - 1];
#pragma unroll
    for (int i = 0; i < 4; ++i) {
        bstart[b0 + i] = run;
        bcursor[b0 + i] = run;
        run += local[i];
    }
    if (tid == 1023) { bstart[NBUCK] = run; rs[N_LINKS] = run; }
}

// Per-block reservation partition into buckets; entry = {first:18 | dst&63:6}.
#define FILL_BLOCKS 128
#define FILL_THREADS 1024
__global__ void __launch_bounds__(FILL_THREADS)
k_fill(const int* __restrict__ first, const int* __restrict__ second,
       int* __restrict__ bcursor, unsigned* __restrict__ sortedA) {
    __shared__ int h[NBUCK];
    __shared__ int resv[NBUCK];
    const int chunk = N_PAIRS / FILL_BLOCKS;   // 32768
    const int base = blockIdx.x * chunk;
    for (int i = threadIdx.x; i < NBUCK; i += blockDim.x) h[i] = 0;
    __syncthreads();
    for (int i = threadIdx.x; i < chunk; i += blockDim.x)
        atomicAdd(&h[second[base + i] >> 6], 1);
    __syncthreads();
    for (int i = threadIdx.x; i < NBUCK; i += blockDim.x) {
        int c = h[i];
        resv[i] = c ? atomicAdd(&bcursor[i], c) : 0;
        h[i] = 0;  // reuse as local cursor
    }
    __syncthreads();
    for (int i = threadIdx.x; i < chunk; i += blockDim.x) {
        int s = second[base + i];
        int b = s >> 6;
        int pos = resv[b] + atomicAdd(&h[b], 1);
        sortedA[pos] = (unsigned)first[base + i] | ((unsigned)(s & 63) << 18);
    }
}

// One block per bucket: in-LDS counting sort -> per-link CSR (rs + srcs).
__global__ void __launch_bounds__(256)
k_refine(const int* __restrict__ bstart, const unsigned* __restrict__ sortedA,
         int* __restrict__ srcs, int* __restrict__ rs) {
    __shared__ unsigned ent[BCAP];
    __shared__ int outv[BCAP];
    __shared__ int cnt[LPB];
    __shared__ int off[LPB];
    const int b = blockIdx.x;
    const int s = bstart[b];
    int n = bstart[b + 1] - s;
    if (n > BCAP) n = BCAP;  // statistically impossible (mean 1024, 30+ sigma)
    for (int i = threadIdx.x; i < n; i += 256) ent[i] = sortedA[s + i];
    if (threadIdx.x < LPB) cnt[threadIdx.x] = 0;
    __syncthreads();
    for (int i = threadIdx.x; i < n; i += 256)
        atomicAdd(&cnt[ent[i] >> 18], 1);
    __syncthreads();
    if (threadIdx.x < LPB) {
        int acc = 0;
        for (int j = 0; j < threadIdx.x; ++j) acc += cnt[j];
        off[threadIdx.x] = acc;
        rs[b * LPB + threadIdx.x] = s + acc;
    }
    __syncthreads();
    for (int i = threadIdx.x; i < n; i += 256) {
        unsigned v = ent[i];
        int pos = atomicAdd(&off[v >> 18], 1);
        outv[pos] = (int)(v & 0x3FFFF);
    }
    __syncthreads();
    for (int i = threadIdx.x; i < n; i += 256) srcs[s + i] = outv[i];
}

// ---------------- per-iteration kernels ----------------

// X1h[l] = fp16(W1 @ state[l] + b_msg), padded 64B rows ; X2[l] = W2 @ state[l]
__global__ void k_premsg(const float* __restrict__ state,
                         const float* __restrict__ W_msg,
                         const float* __restrict__ b_msg,
                         __half* __restrict__ X1h, float* __restrict__ X2) {
    __shared__ float Wl[F * 2 * F];
    __shared__ float bl[F];
    for (int i = threadIdx.x; i < F * 2 * F; i += blockDim.x) Wl[i] = W_msg[i];
    if (threadIdx.x < F) bl[threadIdx.x] = b_msg[threadIdx.x];
    __syncthreads();

    int l = blockIdx.x * blockDim.x + threadIdx.x;

    float s[F];
    const float4* sp = (const float4*)(state + (size_t)l * F);
#pragma unroll
    for (int i = 0; i < 5; ++i) {
        float4 v = sp[i];
        s[4*i+0] = v.x; s[4*i+1] = v.y; s[4*i+2] = v.z; s[4*i+3] = v.w;
    }
    float o1[F], o2[F];
#pragma unroll
    for (int o = 0; o < F; ++o) {
        float a1 = bl[o], a2 = 0.0f;
#pragma unroll
        for (int k = 0; k < F; ++k) {
            a1 = fmaf(Wl[o * 2 * F + k],     s[k], a1);
            a2 = fmaf(Wl[o * 2 * F + F + k], s[k], a2);
        }
        o1[o] = a1; o2[o] = a2;
    }
    __half2* xp = (__half2*)(X1h + (size_t)l * XS);
#pragma unroll
    for (int i = 0; i < 10; ++i)
        xp[i] = __halves2half2(__float2half(o1[2*i]), __float2half(o1[2*i+1]));
    float4* x2p = (float4*)(X2 + (size_t)l * F);
#pragma unroll
    for (int i = 0; i < 5; ++i)
        x2p[i] = make_float4(o2[4*i], o2[4*i+1], o2[4*i+2], o2[4*i+3]);
}

// Wave-per-link gather-aggregate, high-MLP layout:
// lane l: f = l&31 (feature, valid f<20), half = l>>5 (which pair of the round).
// Round r covers pairs 2r, 2r+1 -> one 64-lane VMEM = 2 cache lines; rounds
// are independent (srcs preloaded into a register, broadcast via shuffles).
__global__ void __launch_bounds__(256)
k_agg(const int* __restrict__ rs, const int* __restrict__ srcs,
      const __half* __restrict__ X1h, const float* __restrict__ X2,
      float* __restrict__ agg) {
    const int wave = threadIdx.x >> 6;
    const int l = blockIdx.x * 4 + wave;
    const int lane = threadIdx.x & 63;
    const int f = lane & 31;
    const int half = lane >> 5;

    const float x2f = X2[(size_t)l * F + (f < F ? f : F - 1)];
    const int row_start = rs[l];
    const int cnt = rs[l + 1] - row_start;

    float acc = 0.0f;
    for (int base = 0; base < cnt; base += 64) {
        const int nc = min(64, cnt - base);
        // coalesced preload of up to 64 src indices (clamped duplicate tail)
        const int s_reg = srcs[row_start + base + min(lane, nc - 1)];
        const int rounds = (nc + 1) >> 1;
#pragma unroll 4
        for (int r = 0; r < rounds; ++r) {
            const int i = (r << 1) + half;
            const int idx = min(i, nc - 1);
            const int src = __shfl(s_reg, idx, 64);
            const float x1 = __half2float(X1h[(size_t)src * XS + f]);
            const float v = selu_f(x1 + x2f);
            acc += (i < nc) ? v : 0.0f;
        }
    }
    // lanes l and l^32 hold the same feature f
    acc += __shfl(acc, lane ^ 32, 64);
    if (lane < F) agg[(size_t)l * F + lane] = acc;
}

// GRU fused with next-iteration premsg (flags&1) and feature reduce (flags&2).
__global__ void __launch_bounds__(256)
k_gru(const float* __restrict__ agg, const float* __restrict__ h_in,
      const float* __restrict__ W_ih, const float* __restrict__ W_hh,
      const float* __restrict__ b_ih, const float* __restrict__ b_hh,
      const float* __restrict__ W_msg, const float* __restrict__ b_msg,
      float* __restrict__ h_out, __half* __restrict__ X1h, float* __restrict__ X2,
      float* __restrict__ feature, int flags) {
    __shared__ float Wi[3 * F * F];
    __shared__ float Wh[3 * F * F];
    __shared__ float Wm[F * 2 * F];
    __shared__ float bi[3 * F];
    __shared__ float bh[3 * F];
    __shared__ float bm[F];
    __shared__ float red[4 * F];
    for (int i = threadIdx.x; i < 3 * F * F; i += blockDim.x) {
        Wi[i] = W_ih[i];
        Wh[i] = W_hh[i];
    }
    for (int i = threadIdx.x; i < F * 2 * F; i += blockDim.x) Wm[i] = W_msg[i];
    if (threadIdx.x < 3 * F) {
        bi[threadIdx.x] = b_ih[threadIdx.x];
        bh[threadIdx.x] = b_hh[threadIdx.x];
    }
    if (threadIdx.x < F) bm[threadIdx.x] = b_msg[threadIdx.x];
    __syncthreads();

    const int l = blockIdx.x * blockDim.x + threadIdx.x;

    float m[F], h[F];
    const float4* mp = (const float4*)(agg  + (size_t)l * F);
    const float4* hp = (const float4*)(h_in + (size_t)l * F);
#pragma unroll
    for (int i = 0; i < 5; ++i) {
        float4 vm = mp[i], vh = hp[i];
        m[4*i+0] = vm.x; m[4*i+1] = vm.y; m[4*i+2] = vm.z; m[4*i+3] = vm.w;
        h[4*i+0] = vh.x; h[4*i+1] = vh.y; h[4*i+2] = vh.z; h[4*i+3] = vh.w;
    }

    float hn[F];
#pragma unroll
    for (int j = 0; j < F; ++j) {
        float gr = bi[j]     + bh[j];
        float gz = bi[F + j] + bh[F + j];
        float gi_n = bi[2*F + j];
        float gh_n = bh[2*F + j];
        float gr_i = 0.f, gz_i = 0.f, gr_h = 0.f, gz_h = 0.f;
#pragma unroll
        for (int k = 0; k < F; ++k) {
            gr_i = fmaf(Wi[(0*F + j) * F + k], m[k], gr_i);
            gz_i = fmaf(Wi[(1*F + j) * F + k], m[k], gz_i);
            gi_n = fmaf(Wi[(2*F + j) * F + k], m[k], gi_n);
            gr_h = fmaf(Wh[(0*F + j) * F + k], h[k], gr_h);
            gz_h = fmaf(Wh[(1*F + j) * F + k], h[k], gz_h);
            gh_n = fmaf(Wh[(2*F + j) * F + k], h[k], gh_n);
        }
        float r = sigmoid_f(gr + gr_i + gr_h);
        float z = sigmoid_f(gz + gz_i + gz_h);
        float n = tanh_fast(gi_n + r * gh_n);
        hn[j] = (1.0f - z) * n + z * h[j];
    }

    float4* op = (float4*)(h_out + (size_t)l * F);
#pragma unroll
    for (int i = 0; i < 5; ++i)
        op[i] = make_float4(hn[4*i], hn[4*i+1], hn[4*i+2], hn[4*i+3]);

    if (flags & 1) {  // premsg for next iteration from hn
        float o1[F], o2[F];
#pragma unroll
        for (int o = 0; o < F; ++o) {
            float a1 = bm[o], a2 = 0.0f;
#pragma unroll
            for (int k = 0; k < F; ++k) {
                a1 = fmaf(Wm[o * 2 * F + k],     hn[k], a1);
                a2 = fmaf(Wm[o * 2 * F + F + k], hn[k], a2);
            }
            o1[o] = a1; o2[o] = a2;
        }
        __half2* xp = (__half2*)(X1h + (size_t)l * XS);
#pragma unroll
        for (int i = 0; i < 10; ++i)
            xp[i] = __halves2half2(__float2half(o1[2*i]), __float2half(o1[2*i+1]));
        float4* x2p = (float4*)(X2 + (size_t)l * F);
#pragma unroll
        for (int i = 0; i < 5; ++i)
            x2p[i] = make_float4(o2[4*i], o2[4*i+1], o2[4*i+2], o2[4*i+3]);
    }

    if (flags & 2) {  // feature reduction: sum hn over all links
#pragma unroll
        for (int off = 1; off < 64; off <<= 1) {
#pragma unroll
            for (int j = 0; j < F; ++j) hn[j] += __shfl_xor(hn[j], off, 64);
        }
        const int lane = threadIdx.x & 63;
        const int wave = threadIdx.x >> 6;
        if (lane == 0) {
#pragma unroll
            for (int j = 0; j < F; ++j) red[wave * F + j] = hn[j];
        }
        __syncthreads();
        if (threadIdx.x < F) {
            float s = red[threadIdx.x] + red[F + threadIdx.x] +
                      red[2 * F + threadIdx.x] + red[3 * F + threadIdx.x];
            atomicAdd(&feature[threadIdx.x], s);
        }
    }
}

__global__ void k_readout(const float* __restrict__ feature,
                          const float* __restrict__ W_r1, const float* __restrict__ b_r1,
                          const float* __restrict__ W_r2, const float* __restrict__ b_r2,
                          const float* __restrict__ W_out, const float* __restrict__ b_out,
                          float* __restrict__ out) {
    if (threadIdx.x != 0 || blockIdx.x != 0) return;
    float fv[F], h1[F], h2[F];
#pragma unroll
    for (int i = 0; i < F; ++i) fv[i] = feature[i];
#pragma unroll
    for (int o = 0; o < F; ++o) {
        float a = b_r1[o];
#pragma unroll
        for (int k = 0; k < F; ++k) a = fmaf(W_r1[o * F + k], fv[k], a);
        h1[o] = selu_f(a);
    }
#pragma unroll
    for (int o = 0; o < F; ++o) {
        float a = b_r2[o];
#pragma unroll
        for (int k = 0; k < F; ++k) a = fmaf(W_r2[o * F + k], h1[k], a);
        h2[o] = selu_f(a);
    }
    float a = b_out[0];
#pragma unroll
    for (int k = 0; k < F; ++k) a = fmaf(W_out[k], h2[k], a);
    out[0] = a;
}

extern "C" void kernel_launch(void* const* d_in, const int* in_sizes, int n_in,
                              void* d_out, int out_size, void* d_ws, size_t ws_size,
                              hipStream_t stream) {
    const float* link_state = (const float*)d_in[0];
    const int*   first      = (const int*)  d_in[1];
    const int*   second     = (const int*)  d_in[2];
    // d_in[3] = state_dim (unused)
    const float* W_msg = (const float*)d_in[4];
    const float* b_msg = (const float*)d_in[5];
    const float* W_ih  = (const float*)d_in[6];
    const float* W_hh  = (const float*)d_in[7];
    const float* b_ih  = (const float*)d_in[8];
    const float* b_hh  = (const float*)d_in[9];
    const float* W_r1  = (const float*)d_in[10];
    const float* b_r1  = (const float*)d_in[11];
    const float* W_r2  = (const float*)d_in[12];
    const float* b_r2  = (const float*)d_in[13];
    const float* W_out = (const float*)d_in[14];
    const float* b_out = (const float*)d_in[15];
    float* out = (float*)d_out;

    const size_t NF = (size_t)N_LINKS * F;
    float* state   = (float*)d_ws;                    // 21 MB
    float* X2      = state + NF;                      // 21 MB
    float* agg     = X2 + NF;                         // 21 MB (aliases sortedA)
    __half* X1h    = (__half*)(agg + NF);             // 16.8 MB (64B rows)
    int*    srcs   = (int*)(X1h + (size_t)N_LINKS * XS);  // 16.8 MB
    int*    rs     = srcs + N_PAIRS;                  // 1 MB (+1)
    float* feature = (float*)(rs + N_LINKS + 1);      // 128 B slot
    int* bhist     = (int*)(feature + 32);
    int* bstart    = bhist + NBUCK;                   // NBUCK+1
    int* bcursor   = bstart + NBUCK + 1;
    unsigned* sortedA = (unsigned*)agg;               // lifetime: fill..refine only

    hipMemsetAsync(bhist, 0, NBUCK * sizeof(int), stream);
    hipMemsetAsync(feature, 0, F * sizeof(float), stream);

    k_hist<<<128, 512, 0, stream>>>(second, bhist);
    k_scan<<<1, 1024, 0, stream>>>(bhist, bstart, bcursor, rs);
    k_fill<<<FILL_BLOCKS, FILL_THREADS, 0, stream>>>(first, second, bcursor, sortedA);
    k_refine<<<NBUCK, 256, 0, stream>>>(bstart, sortedA, srcs, rs);

    k_premsg<<<N_LINKS / 256, 256, 0, stream>>>(link_state, W_msg, b_msg, X1h, X2);
    for (int t = 0; t < T_ITERS; ++t) {
        const float* h = (t == 0) ? link_state : state;
        int flags = (t < T_ITERS - 1 ? 1 : 0) | (t == T_ITERS - 1 ? 2 : 0);
        k_agg<<<N_LINKS / 4, 256, 0, stream>>>(rs, srcs, X1h, X2, agg);
        k_gru<<<N_LINKS / 256, 256, 0, stream>>>(agg, h, W_ih, W_hh, b_ih, b_hh,
                                                 W_msg, b_msg, state, X1h, X2,
                                                 feature, flags);
    }
    k_readout<<<1, 64, 0, stream>>>(feature, W_r1, b_r1, W_r2, b_r2, W_out, b_out, out);
}